// Round 6
// baseline (12448.365 us; speedup 1.0000x reference)
//
#include <hip/hip_runtime.h>
#include <hip/hip_bf16.h>
#include <hip/hip_fp16.h>
#include <stdint.h>

typedef short bf16x8 __attribute__((ext_vector_type(8)));
typedef float f32x4  __attribute__((ext_vector_type(4)));
typedef __hip_bfloat16 bf16;

#define MFMA16(a,b,c) __builtin_amdgcn_mfma_f32_16x16x32_bf16((a),(b),(c),0,0,0)

__device__ __forceinline__ float bf2f(bf16 x){ return __bfloat162float(x); }
__device__ __forceinline__ bf16  f2bf(float x){ return __float2bfloat16(x); }
// sanitize raw f32 inputs: kill NaN/inf
__device__ __forceinline__ float sf(float x){ return (fabsf(x) < 1e30f) ? x : 0.f; }

// Problem: B=128, L=256, H=512, OUT=256. All I/O float32. Chunked: 8 x 32 steps.
#define NB   128
#define NL   256
#define CH   32     // steps per chunk
#define MCH  4096   // rows per chunk = CH*NB
#define NQ   8      // chunks

// ---------------- weight preprocessing (f32 in -> bf16 internal) ----------------

__global__ void build_wcatT(const float* __restrict__ Wx, const float* __restrict__ Wm,
                            bf16* __restrict__ dst) {
    int i = blockIdx.x * 256 + threadIdx.x;
    if (i >= 1536 * 1024) return;
    int n = i >> 10, k = i & 1023;
    float v = (k < 512) ? Wx[k * 1536 + n] : Wm[(k - 512) * 1536 + n];
    dst[i] = f2bf(sf(v));
}

__global__ void transpose_f2b(const float* __restrict__ src, bf16* __restrict__ dst,
                              int R, int C) {
    int i = blockIdx.x * 256 + threadIdx.x;
    if (i >= R * C) return;
    int r = i % R, c = i / R;
    dst[i] = f2bf(sf(src[r * C + c]));
}

// ---------------- x-path (h-independent) ----------------

__global__ void xmean_kernel(const int* __restrict__ mask, const float* __restrict__ Cmat,
                             float* __restrict__ xmean) {
    int g = blockIdx.x * 256 + threadIdx.x;   // (b,h)
    int b = g >> 9, h = g & 511;
    float s = 0.f, cnt = 0.f;
    for (int l = 0; l < NL; ++l) {
        int m = mask[(size_t)((b << 8) + l) * 512 + h];
        if (m) { s += sf(Cmat[(l << 9) + h]); cnt += 1.f; }
    }
    xmean[g] = s / fmaxf(cnt, 1.f);
}

__global__ void prep_kernel(const int* __restrict__ mask, const float* __restrict__ Cmat,
                            const float* __restrict__ t_in,
                            const float* __restrict__ w_gx, const float* __restrict__ b_gx,
                            const float* __restrict__ xmean,
                            float* __restrict__ xlastC, float* __restrict__ dprevC,
                            float* __restrict__ mprevC, float* __restrict__ tprevC,
                            bf16* __restrict__ Xcat,   // (4096,1024) l-major: [x_hat|m]
                            bf16* __restrict__ Dbuf,   // (4096,512) l-major: delta
                            int q) {
    int g = blockIdx.x * 256 + threadIdx.x;
    int b = g >> 9, h = g & 511;
    float wg = sf(w_gx[h]), bg = sf(b_gx[h]);
    float xm = xmean[g];
    float xlast, dprev, mprev, tprev;
    if (q == 0) { xlast = xm; dprev = 0.f; mprev = 1.f; tprev = 0.f; }
    else { xlast = xlastC[g]; dprev = dprevC[g]; mprev = mprevC[g]; tprev = tprevC[g]; }
    for (int ll = 0; ll < CH; ++ll) {
        int l = q * CH + ll;
        float tc = sf(t_in[(b << 8) + l]);
        float dtv = (l == 0) ? 0.f : (tc - tprev);
        tprev = tc;
        float mi = (float)mask[(size_t)((b << 8) + l) * 512 + h];
        float delta = dtv + (1.f - mprev) * dprev;
        float gx = __expf(-fmaxf(wg * delta + bg, 0.f));
        float xi = sf(Cmat[(l << 9) + h]);
        float xh = mi * xi + (1.f - mi) * (gx * xlast + (1.f - gx) * xm);
        size_t row = (size_t)ll * 128 + b;           // l-major chunk row
        Xcat[row * 1024 + h]       = f2bf(xh);
        Xcat[row * 1024 + 512 + h] = f2bf(mi);
        Dbuf[row * 512 + h]        = f2bf(delta);
        xlast = mi * xi + (1.f - mi) * xlast;
        dprev = delta; mprev = mi;
    }
    xlastC[g] = xlast; dprevC[g] = dprev; mprevC[g] = mprev; tprevC[g] = tprev;
}

// ---------------- tiled MFMA GEMM, A (MxK) row-major bf16, BT (NxK) row-major bf16 ----
// MODE 0: bf16 out = acc+bias ; MODE 1: fp16 out = exp(-relu(acc+bias)) ;
// MODE 2: f32 out = acc+bias with chunk-row remap (l-major -> (b,l))
template <int MODE>
__global__ __launch_bounds__(256) void gemm_bt(const bf16* __restrict__ A,
                                               const bf16* __restrict__ BT,
                                               const float* __restrict__ bias,
                                               void* __restrict__ Cout,
                                               int N, int K, int q) {
    const int nb = N >> 7;
    int bn = blockIdx.x % nb, bm = blockIdx.x / nb;
    __shared__ bf16 As[4096];   // [kc][row] 16B chunks
    __shared__ bf16 Bs[4096];
    int tid = threadIdx.x, lane = tid & 63, w = tid >> 6;
    int wm = w >> 1, wn = w & 1;
    int quad = lane >> 4, l15 = lane & 15;
    f32x4 acc[4][4];
    #pragma unroll
    for (int i = 0; i < 4; ++i)
        #pragma unroll
        for (int j = 0; j < 4; ++j) acc[i][j] = (f32x4){0.f, 0.f, 0.f, 0.f};

    for (int k0 = 0; k0 < K; k0 += 32) {
        bf16x8 av[2], bv[2];
        #pragma unroll
        for (int cc = 0; cc < 2; ++cc) {
            int c = tid + cc * 256;
            int row = c >> 2, kc = c & 3;
            av[cc] = *(const bf16x8*)(A  + (size_t)(bm * 128 + row) * K + k0 + kc * 8);
            bv[cc] = *(const bf16x8*)(BT + (size_t)(bn * 128 + row) * K + k0 + kc * 8);
        }
        __syncthreads();
        #pragma unroll
        for (int cc = 0; cc < 2; ++cc) {
            int c = tid + cc * 256;
            int row = c >> 2, kc = c & 3;
            *(bf16x8*)&As[(kc * 128 + row) * 8] = av[cc];
            *(bf16x8*)&Bs[(kc * 128 + row) * 8] = bv[cc];
        }
        __syncthreads();
        bf16x8 af[4], bfr[4];
        #pragma unroll
        for (int mt = 0; mt < 4; ++mt)
            af[mt] = *(const bf16x8*)&As[(quad * 128 + wm * 64 + mt * 16 + l15) * 8];
        #pragma unroll
        for (int nt = 0; nt < 4; ++nt)
            bfr[nt] = *(const bf16x8*)&Bs[(quad * 128 + wn * 64 + nt * 16 + l15) * 8];
        #pragma unroll
        for (int mt = 0; mt < 4; ++mt)
            #pragma unroll
            for (int nt = 0; nt < 4; ++nt)
                acc[mt][nt] = MFMA16(af[mt], bfr[nt], acc[mt][nt]);
    }
    int row0 = bm * 128 + wm * 64, col0 = bn * 128 + wn * 64;
    #pragma unroll
    for (int mt = 0; mt < 4; ++mt) {
        #pragma unroll
        for (int nt = 0; nt < 4; ++nt) {
            int col = col0 + nt * 16 + l15;
            float bvf = sf(bias[col]);
            #pragma unroll
            for (int r = 0; r < 4; ++r) {
                int row = row0 + mt * 16 + quad * 4 + r;
                float v = acc[mt][nt][r] + bvf;
                if (MODE == 1)
                    ((__half*)Cout)[(size_t)row * N + col] = __float2half(__expf(-fmaxf(v, 0.f)));
                else if (MODE == 2) {
                    int bb = row & 127, lloc = row >> 7;
                    ((float*)Cout)[(size_t)((bb << 8) + q * CH + lloc) * N + col] = v;
                } else
                    ((bf16*)Cout)[(size_t)row * N + col] = f2bf(v);
            }
        }
    }
}

// ---------------- sequential h-scan: ONE WG per 16 batch rows, zero global sync ----
// 8 blocks x 1024 threads (16 waves). Wave wi owns cols [wi*32,+32) of z, r, ht.
// ALL of Wh (1536x512 bf16 = 384 regs/lane) register-stationary across the WG's
// 2MB aggregate register file (VGPR+AGPR unified on gfx950; MFMA reads B from AGPR).
// r->ht and h-update exchanges are intra-WG LDS + __syncthreads (~100ns), replacing
// r5's 2 LLC flag-syncs/step (~7us/step).
__global__ __launch_bounds__(1024, 1) void scan_kernel(
        const bf16* __restrict__ pre,      // (4096,1536) l-major
        const __half* __restrict__ gammaf, // (4096,512) l-major
        const bf16* __restrict__ WhT,      // (1536,512)
        bf16* __restrict__ hseq,           // (4096,512) l-major
        float* __restrict__ hcarry) {      // (128,512)
    int c = blockIdx.x;                    // batch rows [c*16, c*16+16)
    int tid = threadIdx.x;
    int lane = tid & 63, wi = tid >> 6;    // wi in [0,16)
    int quad = lane >> 4, l15 = lane & 15;
    __shared__ float hf[16 * 520];         // h state f32 (padded stride)
    __shared__ bf16  hb[16 * 520];         // h state bf16 (MFMA A source)
    __shared__ bf16  rh[16 * 520];         // r*h bf16 (MFMA A source)

    // stationary Wh B-fragments: B[n=l15][k=quad*8+j] per kf block of K=32
    bf16x8 whz[2][16], whr[2][16], whh[2][16];
    int col0 = wi * 32;                    // owned 32-col slice within each gate
    #pragma unroll
    for (int tt = 0; tt < 2; ++tt)
        #pragma unroll
        for (int kf = 0; kf < 16; ++kf) {
            int n = col0 + tt * 16 + l15;
            whz[tt][kf] = *(const bf16x8*)(WhT + (size_t)n * 512 + kf * 32 + quad * 8);
            whr[tt][kf] = *(const bf16x8*)(WhT + (size_t)(512 + n) * 512 + kf * 32 + quad * 8);
            whh[tt][kf] = *(const bf16x8*)(WhT + (size_t)(1024 + n) * 512 + kf * 32 + quad * 8);
        }

    // init h = hcarry * gamma(local step 0)
    for (int i = tid; i < 16 * 512; i += 1024) {
        int row = i >> 9, col = i & 511;
        int brow = c * 16 + row;
        float g0 = __half2float(gammaf[(size_t)brow * 512 + col]);
        float h0 = hcarry[(size_t)brow * 512 + col] * g0;
        hf[row * 520 + col] = h0;
        hb[row * 520 + col] = f2bf(h0);
    }
    __syncthreads();

    for (int t = 0; t < CH; ++t) {
        // ---- phase A: z (keep in regs), r -> rh = bf16(r * h) into LDS ----
        f32x4 az[2], ar[2];
        az[0] = az[1] = ar[0] = ar[1] = (f32x4){0.f, 0.f, 0.f, 0.f};
        #pragma unroll
        for (int kf = 0; kf < 16; ++kf) {
            bf16x8 a = *(const bf16x8*)&hb[l15 * 520 + kf * 32 + quad * 8];
            az[0] = MFMA16(a, whz[0][kf], az[0]);
            az[1] = MFMA16(a, whz[1][kf], az[1]);
            ar[0] = MFMA16(a, whr[0][kf], ar[0]);
            ar[1] = MFMA16(a, whr[1][kf], ar[1]);
        }
        float zv[2][4];
        #pragma unroll
        for (int tt = 0; tt < 2; ++tt)
            #pragma unroll
            for (int r = 0; r < 4; ++r) {
                int row = quad * 4 + r;
                int brow = c * 16 + row;
                size_t prow = ((size_t)t * 128 + brow) * 1536;
                int cc = col0 + tt * 16 + l15;
                float xz = az[tt][r] + bf2f(pre[prow + cc]);
                zv[tt][r] = 1.f / (1.f + __expf(-xz));
                float xr = ar[tt][r] + bf2f(pre[prow + 512 + cc]);
                float rv = 1.f / (1.f + __expf(-xr));
                rh[row * 520 + cc] = f2bf(rv * hf[row * 520 + cc]);
            }
        __syncthreads();
        // ---- phase B: ht = tanh(pre3 + rh @ Wh3); h_new local; update state ----
        f32x4 ah[2];
        ah[0] = ah[1] = (f32x4){0.f, 0.f, 0.f, 0.f};
        #pragma unroll
        for (int kf = 0; kf < 16; ++kf) {
            bf16x8 a = *(const bf16x8*)&rh[l15 * 520 + kf * 32 + quad * 8];
            ah[0] = MFMA16(a, whh[0][kf], ah[0]);
            ah[1] = MFMA16(a, whh[1][kf], ah[1]);
        }
        #pragma unroll
        for (int tt = 0; tt < 2; ++tt)
            #pragma unroll
            for (int r = 0; r < 4; ++r) {
                int row = quad * 4 + r;
                int brow = c * 16 + row;
                int cc = col0 + tt * 16 + l15;
                float x = ah[tt][r] + bf2f(pre[((size_t)t * 128 + brow) * 1536 + 1024 + cc]);
                float e = __expf(-2.f * fabsf(x));
                float th = copysignf((1.f - e) / (1.f + e), x);
                float hd = hf[row * 520 + cc];
                float z = zv[tt][r];
                float hn = (1.f - z) * hd + z * th;
                hseq[((size_t)t * 128 + brow) * 512 + cc] = f2bf(hn);
                float hx;
                if (t < CH - 1) {
                    hx = hn * __half2float(gammaf[((size_t)(t + 1) * 128 + brow) * 512 + cc]);
                } else {
                    hcarry[(size_t)brow * 512 + cc] = hn;   // raw carry
                    hx = hn;
                }
                hf[row * 520 + cc] = hx;
                hb[row * 520 + cc] = f2bf(hx);
            }
        __syncthreads();
    }
}

// ---------------- launcher ----------------

extern "C" void kernel_launch(void* const* d_in, const int* in_sizes, int n_in,
                              void* d_out, int out_size, void* d_ws, size_t ws_size,
                              hipStream_t stream) {
    const float* C     = (const float*)d_in[0];
    const float* t_in  = (const float*)d_in[1];
    const int*   mask  = (const int*)d_in[2];
    const float* Wx    = (const float*)d_in[3];
    const float* Wh    = (const float*)d_in[4];
    const float* Wm    = (const float*)d_in[5];
    const float* bvec  = (const float*)d_in[6];
    const float* w_gx  = (const float*)d_in[7];
    const float* b_gx  = (const float*)d_in[8];
    const float* W_gh  = (const float*)d_in[9];
    const float* b_gh  = (const float*)d_in[10];
    const float* W_out = (const float*)d_in[11];
    const float* b_out = (const float*)d_in[12];

    char* w = (char*)d_ws;                              // total used: ~41.2 MB
    float* hcarry   = (float*)(w + 16384);              //  262144
    float* xmean    = (float*)(w + 278528);             //  262144
    float* xlastC   = (float*)(w + 540672);             //  262144
    float* dprevC   = (float*)(w + 802816);             //  262144
    float* mprevC   = (float*)(w + 1064960);            //  262144
    float* tprevC   = (float*)(w + 1327104);            //  262144
    bf16*  wcatT    = (bf16*)(w + 1589248);             // 3145728
    bf16*  wghT     = (bf16*)(w + 4734976);             //  524288
    bf16*  whT      = (bf16*)(w + 5259264);             // 1572864
    bf16*  woutT    = (bf16*)(w + 6832128);             //  262144
    bf16*  Xcat     = (bf16*)(w + 7094272);             //  8388608 (chunk)
    bf16*  Dbuf     = (bf16*)(w + 15482880);            //  4194304 (chunk)
    bf16*  pre      = (bf16*)(w + 19677184);            // 12582912 (chunk)
    __half* gamma   = (__half*)(w + 32260096);          //  4194304 (chunk)
    bf16*  hseq     = (bf16*)(w + 36454400);            //  4194304 (chunk)

    hipMemsetAsync(w, 0, 278528, stream);               // hcarry (+ pad)

    build_wcatT<<<6144, 256, 0, stream>>>(Wx, Wm, wcatT);
    transpose_f2b<<<1024, 256, 0, stream>>>(W_gh, wghT, 512, 512);
    transpose_f2b<<<3072, 256, 0, stream>>>(Wh, whT, 512, 1536);
    transpose_f2b<<<512, 256, 0, stream>>>(W_out, woutT, 512, 256);
    xmean_kernel<<<256, 256, 0, stream>>>(mask, C, xmean);

    for (int q = 0; q < NQ; ++q) {
        prep_kernel<<<256, 256, 0, stream>>>(mask, C, t_in, w_gx, b_gx, xmean,
                                             xlastC, dprevC, mprevC, tprevC,
                                             Xcat, Dbuf, q);
        gemm_bt<0><<<32 * 12, 256, 0, stream>>>(Xcat, wcatT, bvec, (void*)pre, 1536, 1024, q);
        gemm_bt<1><<<32 * 4, 256, 0, stream>>>(Dbuf, wghT, b_gh, (void*)gamma, 512, 512, q);
        scan_kernel<<<8, 1024, 0, stream>>>(pre, gamma, whT, hseq, hcarry);
        gemm_bt<2><<<32 * 2, 256, 0, stream>>>(hseq, woutT, b_out, d_out, 256, 512, q);
    }
}

// Round 7
// 3519.881 us; speedup vs baseline: 3.5366x; 3.5366x over previous
//
#include <hip/hip_runtime.h>
#include <hip/hip_bf16.h>
#include <hip/hip_fp16.h>
#include <stdint.h>

typedef short bf16x8 __attribute__((ext_vector_type(8)));
typedef unsigned short u16x8 __attribute__((ext_vector_type(8)));
typedef float f32x4  __attribute__((ext_vector_type(4)));
typedef __hip_bfloat16 bf16;

#define MFMA16(a,b,c) __builtin_amdgcn_mfma_f32_16x16x32_bf16((a),(b),(c),0,0,0)

__device__ __forceinline__ float bf2f(bf16 x){ return __bfloat162float(x); }
__device__ __forceinline__ bf16  f2bf(float x){ return __float2bfloat16(x); }
__device__ __forceinline__ short f2bs(float x){ bf16 t = __float2bfloat16(x); return *(short*)&t; }
__device__ __forceinline__ float bs2f(short s){ bf16 t; *(short*)&t = s; return __bfloat162float(t); }
__device__ __forceinline__ float h2f(unsigned short u){ __half t; *(unsigned short*)&t = u; return __half2float(t); }
// sanitize raw f32 inputs: kill NaN/inf
__device__ __forceinline__ float sf(float x){ return (fabsf(x) < 1e30f) ? x : 0.f; }

// Problem: B=128, L=256, H=512, OUT=256. All I/O float32. Chunked: 8 x 32 steps.
#define NB   128
#define NL   256
#define CH   32     // steps per chunk
#define MCH  4096   // rows per chunk = CH*NB
#define NQ   8      // chunks

// ---------------- weight preprocessing (f32 in -> bf16 internal) ----------------

__global__ void build_wcatT(const float* __restrict__ Wx, const float* __restrict__ Wm,
                            bf16* __restrict__ dst) {
    int i = blockIdx.x * 256 + threadIdx.x;
    if (i >= 1536 * 1024) return;
    int n = i >> 10, k = i & 1023;
    float v = (k < 512) ? Wx[k * 1536 + n] : Wm[(k - 512) * 1536 + n];
    dst[i] = f2bf(sf(v));
}

__global__ void transpose_f2b(const float* __restrict__ src, bf16* __restrict__ dst,
                              int R, int C) {
    int i = blockIdx.x * 256 + threadIdx.x;
    if (i >= R * C) return;
    int r = i % R, c = i / R;
    dst[i] = f2bf(sf(src[r * C + c]));
}

// ---------------- x-path (h-independent) ----------------

__global__ void xmean_kernel(const int* __restrict__ mask, const float* __restrict__ Cmat,
                             float* __restrict__ xmean) {
    int g = blockIdx.x * 256 + threadIdx.x;   // (b,h)
    int b = g >> 9, h = g & 511;
    float s = 0.f, cnt = 0.f;
    for (int l = 0; l < NL; ++l) {
        int m = mask[(size_t)((b << 8) + l) * 512 + h];
        if (m) { s += sf(Cmat[(l << 9) + h]); cnt += 1.f; }
    }
    xmean[g] = s / fmaxf(cnt, 1.f);
}

__global__ void prep_kernel(const int* __restrict__ mask, const float* __restrict__ Cmat,
                            const float* __restrict__ t_in,
                            const float* __restrict__ w_gx, const float* __restrict__ b_gx,
                            const float* __restrict__ xmean,
                            float* __restrict__ xlastC, float* __restrict__ dprevC,
                            float* __restrict__ mprevC, float* __restrict__ tprevC,
                            bf16* __restrict__ Xcat,   // (4096,1024) l-major: [x_hat|m]
                            bf16* __restrict__ Dbuf,   // (4096,512) l-major: delta
                            int q) {
    int g = blockIdx.x * 256 + threadIdx.x;
    int b = g >> 9, h = g & 511;
    float wg = sf(w_gx[h]), bg = sf(b_gx[h]);
    float xm = xmean[g];
    float xlast, dprev, mprev, tprev;
    if (q == 0) { xlast = xm; dprev = 0.f; mprev = 1.f; tprev = 0.f; }
    else { xlast = xlastC[g]; dprev = dprevC[g]; mprev = mprevC[g]; tprev = tprevC[g]; }
    for (int ll = 0; ll < CH; ++ll) {
        int l = q * CH + ll;
        float tc = sf(t_in[(b << 8) + l]);
        float dtv = (l == 0) ? 0.f : (tc - tprev);
        tprev = tc;
        float mi = (float)mask[(size_t)((b << 8) + l) * 512 + h];
        float delta = dtv + (1.f - mprev) * dprev;
        float gx = __expf(-fmaxf(wg * delta + bg, 0.f));
        float xi = sf(Cmat[(l << 9) + h]);
        float xh = mi * xi + (1.f - mi) * (gx * xlast + (1.f - gx) * xm);
        size_t row = (size_t)ll * 128 + b;           // l-major chunk row
        Xcat[row * 1024 + h]       = f2bf(xh);
        Xcat[row * 1024 + 512 + h] = f2bf(mi);
        Dbuf[row * 512 + h]        = f2bf(delta);
        xlast = mi * xi + (1.f - mi) * xlast;
        dprev = delta; mprev = mi;
    }
    xlastC[g] = xlast; dprevC[g] = dprev; mprevC[g] = mprev; tprevC[g] = tprev;
}

// ---------------- tiled MFMA GEMM, A (MxK) row-major bf16, BT (NxK) row-major bf16 ----
// MODE 0: bf16 out = acc+bias ; MODE 1: fp16 out = exp(-relu(acc+bias)) ;
// MODE 2: f32 out = acc+bias with chunk-row remap (l-major -> (b,l))
template <int MODE>
__global__ __launch_bounds__(256) void gemm_bt(const bf16* __restrict__ A,
                                               const bf16* __restrict__ BT,
                                               const float* __restrict__ bias,
                                               void* __restrict__ Cout,
                                               int N, int K, int q) {
    const int nb = N >> 7;
    int bn = blockIdx.x % nb, bm = blockIdx.x / nb;
    __shared__ bf16 As[4096];   // [kc][row] 16B chunks
    __shared__ bf16 Bs[4096];
    int tid = threadIdx.x, lane = tid & 63, w = tid >> 6;
    int wm = w >> 1, wn = w & 1;
    int quad = lane >> 4, l15 = lane & 15;
    f32x4 acc[4][4];
    #pragma unroll
    for (int i = 0; i < 4; ++i)
        #pragma unroll
        for (int j = 0; j < 4; ++j) acc[i][j] = (f32x4){0.f, 0.f, 0.f, 0.f};

    for (int k0 = 0; k0 < K; k0 += 32) {
        bf16x8 av[2], bv[2];
        #pragma unroll
        for (int cc = 0; cc < 2; ++cc) {
            int c = tid + cc * 256;
            int row = c >> 2, kc = c & 3;
            av[cc] = *(const bf16x8*)(A  + (size_t)(bm * 128 + row) * K + k0 + kc * 8);
            bv[cc] = *(const bf16x8*)(BT + (size_t)(bn * 128 + row) * K + k0 + kc * 8);
        }
        __syncthreads();
        #pragma unroll
        for (int cc = 0; cc < 2; ++cc) {
            int c = tid + cc * 256;
            int row = c >> 2, kc = c & 3;
            *(bf16x8*)&As[(kc * 128 + row) * 8] = av[cc];
            *(bf16x8*)&Bs[(kc * 128 + row) * 8] = bv[cc];
        }
        __syncthreads();
        bf16x8 af[4], bfr[4];
        #pragma unroll
        for (int mt = 0; mt < 4; ++mt)
            af[mt] = *(const bf16x8*)&As[(quad * 128 + wm * 64 + mt * 16 + l15) * 8];
        #pragma unroll
        for (int nt = 0; nt < 4; ++nt)
            bfr[nt] = *(const bf16x8*)&Bs[(quad * 128 + wn * 64 + nt * 16 + l15) * 8];
        #pragma unroll
        for (int mt = 0; mt < 4; ++mt)
            #pragma unroll
            for (int nt = 0; nt < 4; ++nt)
                acc[mt][nt] = MFMA16(af[mt], bfr[nt], acc[mt][nt]);
    }
    int row0 = bm * 128 + wm * 64, col0 = bn * 128 + wn * 64;
    #pragma unroll
    for (int mt = 0; mt < 4; ++mt) {
        #pragma unroll
        for (int nt = 0; nt < 4; ++nt) {
            int col = col0 + nt * 16 + l15;
            float bvf = sf(bias[col]);
            #pragma unroll
            for (int r = 0; r < 4; ++r) {
                int row = row0 + mt * 16 + quad * 4 + r;
                float v = acc[mt][nt][r] + bvf;
                if (MODE == 1)
                    ((__half*)Cout)[(size_t)row * N + col] = __float2half(__expf(-fmaxf(v, 0.f)));
                else if (MODE == 2) {
                    int bb = row & 127, lloc = row >> 7;
                    ((float*)Cout)[(size_t)((bb << 8) + q * CH + lloc) * N + col] = v;
                } else
                    ((bf16*)Cout)[(size_t)row * N + col] = f2bf(v);
            }
        }
    }
}

// ---------------- sequential h-scan over one 32-step chunk ----------------
// r5 structure (8 WGs x 256thr per cluster; wave wi owns 16 cols of each gate;
// 192 weight VGPRs/lane — proven no-spill) + latency cuts:
//  - bf16 exchanges (16KB r + 16KB h per cluster, was 2x32KB f32)
//  - pre(t) + gamma(t+1) prefetched to registers before the fences (fence-immune)
//  - owned h f32 state lives in 4 registers (C/D layout), no f32 LDS array
// Sync: release fetch_add + relaxed polls + one fence after spin (r5-proven).
__global__ __launch_bounds__(256, 1) void scan_kernel(
        const bf16* __restrict__ pre,      // (4096,1536) l-major
        const __half* __restrict__ gammaf, // (4096,512) l-major
        const bf16* __restrict__ WhT,      // (1536,512)
        bf16* __restrict__ hseq,           // (4096,512) l-major
        float* __restrict__ hcarry,        // (128,512)
        bf16* __restrict__ rbuf,           // [8][16][512] bf16
        bf16* __restrict__ hnbuf,          // [8][16][512] bf16
        unsigned* __restrict__ ctr) {      // this chunk's slot (512 uints, zeroed)
    int bx = blockIdx.x;
    int c = bx & 7, w = bx >> 3;           // cluster, WG-in-cluster
    int tid = threadIdx.x, lane = tid & 63, v = tid >> 6;
    int wi = (w << 2) | v;                 // 0..31: owns cols [wi*16,+16) per gate
    int quad = lane >> 4, l15 = lane & 15;
    __shared__ bf16 hb[16 * 520];          // full h, bf16 (MFMA A source)
    __shared__ bf16 rh[16 * 520];          // r*h, bf16 (MFMA A source)

    // stationary Wh B-fragments: B[n=l15][k=quad*8+j] per kf block of K=32
    bf16x8 whz[16], whr[16], whh[16];
    int col0 = wi * 16;
    #pragma unroll
    for (int kf = 0; kf < 16; ++kf) {
        int n = col0 + l15;
        whz[kf] = *(const bf16x8*)(WhT + (size_t)n * 512 + kf * 32 + quad * 8);
        whr[kf] = *(const bf16x8*)(WhT + (size_t)(512 + n) * 512 + kf * 32 + quad * 8);
        whh[kf] = *(const bf16x8*)(WhT + (size_t)(1024 + n) * 512 + kf * 32 + quad * 8);
    }

    bf16* rclu = rbuf  + (size_t)c * 16 * 512;
    bf16* hclu = hnbuf + (size_t)c * 16 * 512;
    const unsigned short* gus = (const unsigned short*)gammaf;

    // init: hb = bf16(hcarry * gamma(step 0)); owned f32 state in hfo
    for (int i = tid; i < 16 * 512; i += 256) {
        int row = i >> 9, col = i & 511;
        int brow = c * 16 + row;
        float g0 = __half2float(gammaf[(size_t)brow * 512 + col]);
        hb[row * 520 + col] = f2bf(hcarry[(size_t)brow * 512 + col] * g0);
    }
    float hfo[4];
    #pragma unroll
    for (int r = 0; r < 4; ++r) {
        int brow = c * 16 + quad * 4 + r;
        int cc = col0 + l15;
        float g0 = __half2float(gammaf[(size_t)brow * 512 + cc]);
        hfo[r] = hcarry[(size_t)brow * 512 + cc] * g0;
    }
    __syncthreads();

    unsigned* ctrA = ctr + c * 32;
    unsigned* ctrB = ctrA + 16;
    int prow = tid >> 4;                   // phase B/C tile: row, 32 contiguous cols
    int pcol = (tid & 15) << 5;

    for (int t = 0; t < CH; ++t) {
        unsigned tgt = 8u * (t + 1);
        bool lastt = (t == CH - 1);
        // ---- register prefetch (consumed after the fences; fence-immune) ----
        float pz[4], prr[4], ph[4], gow[4];
        #pragma unroll
        for (int r = 0; r < 4; ++r) {
            int brow = c * 16 + quad * 4 + r;
            size_t pb = ((size_t)t * 128 + brow) * 1536;
            int cc = col0 + l15;
            pz[r]  = bf2f(pre[pb + cc]);
            prr[r] = bf2f(pre[pb + 512 + cc]);
            ph[r]  = bf2f(pre[pb + 1024 + cc]);
            gow[r] = lastt ? 1.f
                   : __half2float(gammaf[((size_t)(t + 1) * 128 + brow) * 512 + cc]);
        }
        u16x8 gt[4];
        {
            size_t gb = ((size_t)(lastt ? t : t + 1) * 128 + c * 16 + prow) * 512 + pcol;
            #pragma unroll
            for (int j = 0; j < 4; ++j) gt[j] = *(const u16x8*)(gus + gb + j * 8);
        }
        // ---- phase A: z local, publish r (bf16) ----
        f32x4 az = (f32x4){0.f,0.f,0.f,0.f}, ar = az;
        #pragma unroll
        for (int kf = 0; kf < 16; ++kf) {
            bf16x8 a = *(const bf16x8*)&hb[l15 * 520 + kf * 32 + quad * 8];
            az = MFMA16(a, whz[kf], az);
            ar = MFMA16(a, whr[kf], ar);
        }
        float zv[4];
        #pragma unroll
        for (int r = 0; r < 4; ++r) {
            zv[r] = 1.f / (1.f + __expf(-(az[r] + pz[r])));
            float rv = 1.f / (1.f + __expf(-(ar[r] + prr[r])));
            rclu[(quad * 4 + r) * 512 + col0 + l15] = f2bf(rv);
        }
        __syncthreads();                   // drains all waves' stores (vmcnt0)
        if (tid == 0) {
            __hip_atomic_fetch_add(ctrA, 1u, __ATOMIC_RELEASE, __HIP_MEMORY_SCOPE_AGENT);
            int guard = 0;
            while (__hip_atomic_load(ctrA, __ATOMIC_RELAXED, __HIP_MEMORY_SCOPE_AGENT) < tgt
                   && ++guard < (1 << 17))
                __builtin_amdgcn_s_sleep(1);
            __threadfence();
        }
        __syncthreads();
        // ---- phase B: rh = bf16(r ⊙ h); ht; h_new local; publish h_new (bf16) ----
        #pragma unroll
        for (int j = 0; j < 4; ++j) {
            bf16x8 r8 = *(const bf16x8*)&rclu[prow * 512 + pcol + j * 8];
            bf16x8 h8 = *(const bf16x8*)&hb[prow * 520 + pcol + j * 8];
            bf16x8 o;
            #pragma unroll
            for (int e = 0; e < 8; ++e) o[e] = f2bs(bs2f(r8[e]) * bs2f(h8[e]));
            *(bf16x8*)&rh[prow * 520 + pcol + j * 8] = o;
        }
        __syncthreads();
        f32x4 ah = (f32x4){0.f,0.f,0.f,0.f};
        #pragma unroll
        for (int kf = 0; kf < 16; ++kf) {
            bf16x8 a = *(const bf16x8*)&rh[l15 * 520 + kf * 32 + quad * 8];
            ah = MFMA16(a, whh[kf], ah);
        }
        #pragma unroll
        for (int r = 0; r < 4; ++r) {
            int row = quad * 4 + r;
            int brow = c * 16 + row;
            int cc = col0 + l15;
            float x = ah[r] + ph[r];
            float e = __expf(-2.f * fabsf(x));
            float th = copysignf((1.f - e) / (1.f + e), x);
            float hn = (1.f - zv[r]) * hfo[r] + zv[r] * th;
            bf16 hnb = f2bf(hn);
            hclu[row * 512 + cc] = hnb;
            hseq[((size_t)t * 128 + brow) * 512 + cc] = hnb;
            if (lastt) hcarry[(size_t)brow * 512 + cc] = hn;   // raw carry
            hfo[r] = hn * gow[r];
        }
        __syncthreads();
        if (tid == 0) {
            __hip_atomic_fetch_add(ctrB, 1u, __ATOMIC_RELEASE, __HIP_MEMORY_SCOPE_AGENT);
            int guard = 0;
            while (__hip_atomic_load(ctrB, __ATOMIC_RELAXED, __HIP_MEMORY_SCOPE_AGENT) < tgt
                   && ++guard < (1 << 17))
                __builtin_amdgcn_s_sleep(1);
            __threadfence();
        }
        __syncthreads();
        // ---- phase C: hb = bf16(h_new * gamma(t+1)) for all 512 cols ----
        #pragma unroll
        for (int j = 0; j < 4; ++j) {
            bf16x8 h8 = *(const bf16x8*)&hclu[prow * 512 + pcol + j * 8];
            bf16x8 o;
            #pragma unroll
            for (int e = 0; e < 8; ++e) {
                float g = lastt ? 1.f : h2f(gt[j][e]);
                o[e] = f2bs(bs2f(h8[e]) * g);
            }
            *(bf16x8*)&hb[prow * 520 + pcol + j * 8] = o;
        }
        __syncthreads();
    }
}

// ---------------- launcher ----------------

extern "C" void kernel_launch(void* const* d_in, const int* in_sizes, int n_in,
                              void* d_out, int out_size, void* d_ws, size_t ws_size,
                              hipStream_t stream) {
    const float* C     = (const float*)d_in[0];
    const float* t_in  = (const float*)d_in[1];
    const int*   mask  = (const int*)d_in[2];
    const float* Wx    = (const float*)d_in[3];
    const float* Wh    = (const float*)d_in[4];
    const float* Wm    = (const float*)d_in[5];
    const float* bvec  = (const float*)d_in[6];
    const float* w_gx  = (const float*)d_in[7];
    const float* b_gx  = (const float*)d_in[8];
    const float* W_gh  = (const float*)d_in[9];
    const float* b_gh  = (const float*)d_in[10];
    const float* W_out = (const float*)d_in[11];
    const float* b_out = (const float*)d_in[12];

    char* w = (char*)d_ws;                              // total used: ~41 MB
    unsigned* ctr   = (unsigned*)(w + 0);               //   16384 (8 chunk slots)
    float* hcarry   = (float*)(w + 16384);              //  262144
    float* xmean    = (float*)(w + 278528);             //  262144
    float* xlastC   = (float*)(w + 540672);             //  262144
    float* dprevC   = (float*)(w + 802816);             //  262144
    float* mprevC   = (float*)(w + 1064960);            //  262144
    float* tprevC   = (float*)(w + 1327104);            //  262144
    bf16*  wcatT    = (bf16*)(w + 1589248);             // 3145728
    bf16*  wghT     = (bf16*)(w + 4734976);             //  524288
    bf16*  whT      = (bf16*)(w + 5259264);             // 1572864
    bf16*  woutT    = (bf16*)(w + 6832128);             //  262144
    bf16*  Xcat     = (bf16*)(w + 7094272);             //  8388608 (chunk)
    bf16*  Dbuf     = (bf16*)(w + 15482880);            //  4194304 (chunk)
    bf16*  pre      = (bf16*)(w + 19677184);            // 12582912 (chunk)
    __half* gamma   = (__half*)(w + 32260096);          //  4194304 (chunk)
    bf16*  hseq     = (bf16*)(w + 36454400);            //  4194304 (chunk)
    bf16*  rbuf     = (bf16*)(w + 40648704);            //   131072
    bf16*  hnbuf    = (bf16*)(w + 40779776);            //   131072 -> ends 40,910,848

    hipMemsetAsync(w, 0, 278528, stream);               // ctr + hcarry

    build_wcatT<<<6144, 256, 0, stream>>>(Wx, Wm, wcatT);
    transpose_f2b<<<1024, 256, 0, stream>>>(W_gh, wghT, 512, 512);
    transpose_f2b<<<3072, 256, 0, stream>>>(Wh, whT, 512, 1536);
    transpose_f2b<<<512, 256, 0, stream>>>(W_out, woutT, 512, 256);
    xmean_kernel<<<256, 256, 0, stream>>>(mask, C, xmean);

    for (int q = 0; q < NQ; ++q) {
        prep_kernel<<<256, 256, 0, stream>>>(mask, C, t_in, w_gx, b_gx, xmean,
                                             xlastC, dprevC, mprevC, tprevC,
                                             Xcat, Dbuf, q);
        gemm_bt<0><<<32 * 12, 256, 0, stream>>>(Xcat, wcatT, bvec, (void*)pre, 1536, 1024, q);
        gemm_bt<1><<<32 * 4, 256, 0, stream>>>(Dbuf, wghT, b_gh, (void*)gamma, 512, 512, q);
        scan_kernel<<<64, 256, 0, stream>>>(pre, gamma, whT, hseq, hcarry,
                                            rbuf, hnbuf, ctr + q * 512);
        gemm_bt<2><<<32 * 2, 256, 0, stream>>>(hseq, woutT, b_out, d_out, 256, 512, q);
    }
}

// Round 8
// 3437.798 us; speedup vs baseline: 3.6210x; 1.0239x over previous
//
#include <hip/hip_runtime.h>
#include <hip/hip_bf16.h>
#include <hip/hip_fp16.h>
#include <stdint.h>

typedef short bf16x8 __attribute__((ext_vector_type(8)));
typedef unsigned short u16x8 __attribute__((ext_vector_type(8)));
typedef float f32x4  __attribute__((ext_vector_type(4)));
typedef __hip_bfloat16 bf16;

#define MFMA16(a,b,c) __builtin_amdgcn_mfma_f32_16x16x32_bf16((a),(b),(c),0,0,0)

__device__ __forceinline__ float bf2f(bf16 x){ return __bfloat162float(x); }
__device__ __forceinline__ bf16  f2bf(float x){ return __float2bfloat16(x); }
__device__ __forceinline__ short f2bs(float x){ bf16 t = __float2bfloat16(x); return *(short*)&t; }
__device__ __forceinline__ float bs2f(short s){ bf16 t; *(short*)&t = s; return __bfloat162float(t); }
__device__ __forceinline__ float h2f(unsigned short u){ __half t; *(unsigned short*)&t = u; return __half2float(t); }
// sanitize raw f32 inputs: kill NaN/inf
__device__ __forceinline__ float sf(float x){ return (fabsf(x) < 1e30f) ? x : 0.f; }

// Problem: B=128, L=256, H=512, OUT=256. All I/O float32. Chunked: 8 x 32 steps.
#define NB   128
#define NL   256
#define CH   32     // steps per chunk
#define MCH  4096   // rows per chunk = CH*NB
#define NQ   8      // chunks

// ---------------- weight preprocessing (f32 in -> bf16 internal) ----------------

__global__ void build_wcatT(const float* __restrict__ Wx, const float* __restrict__ Wm,
                            bf16* __restrict__ dst) {
    int i = blockIdx.x * 256 + threadIdx.x;
    if (i >= 1536 * 1024) return;
    int n = i >> 10, k = i & 1023;
    float v = (k < 512) ? Wx[k * 1536 + n] : Wm[(k - 512) * 1536 + n];
    dst[i] = f2bf(sf(v));
}

__global__ void transpose_f2b(const float* __restrict__ src, bf16* __restrict__ dst,
                              int R, int C) {
    int i = blockIdx.x * 256 + threadIdx.x;
    if (i >= R * C) return;
    int r = i % R, c = i / R;
    dst[i] = f2bf(sf(src[r * C + c]));
}

// ---------------- x-path (h-independent) ----------------

__global__ void xmean_kernel(const int* __restrict__ mask, const float* __restrict__ Cmat,
                             float* __restrict__ xmean) {
    int g = blockIdx.x * 256 + threadIdx.x;   // (b,h)
    int b = g >> 9, h = g & 511;
    float s = 0.f, cnt = 0.f;
    for (int l = 0; l < NL; ++l) {
        int m = mask[(size_t)((b << 8) + l) * 512 + h];
        if (m) { s += sf(Cmat[(l << 9) + h]); cnt += 1.f; }
    }
    xmean[g] = s / fmaxf(cnt, 1.f);
}

__global__ void prep_kernel(const int* __restrict__ mask, const float* __restrict__ Cmat,
                            const float* __restrict__ t_in,
                            const float* __restrict__ w_gx, const float* __restrict__ b_gx,
                            const float* __restrict__ xmean,
                            float* __restrict__ xlastC, float* __restrict__ dprevC,
                            float* __restrict__ mprevC, float* __restrict__ tprevC,
                            bf16* __restrict__ Xcat,   // (4096,1024) l-major: [x_hat|m]
                            bf16* __restrict__ Dbuf,   // (4096,512) l-major: delta
                            int q) {
    int g = blockIdx.x * 256 + threadIdx.x;
    int b = g >> 9, h = g & 511;
    float wg = sf(w_gx[h]), bg = sf(b_gx[h]);
    float xm = xmean[g];
    float xlast, dprev, mprev, tprev;
    if (q == 0) { xlast = xm; dprev = 0.f; mprev = 1.f; tprev = 0.f; }
    else { xlast = xlastC[g]; dprev = dprevC[g]; mprev = mprevC[g]; tprev = tprevC[g]; }
    for (int ll = 0; ll < CH; ++ll) {
        int l = q * CH + ll;
        float tc = sf(t_in[(b << 8) + l]);
        float dtv = (l == 0) ? 0.f : (tc - tprev);
        tprev = tc;
        float mi = (float)mask[(size_t)((b << 8) + l) * 512 + h];
        float delta = dtv + (1.f - mprev) * dprev;
        float gx = __expf(-fmaxf(wg * delta + bg, 0.f));
        float xi = sf(Cmat[(l << 9) + h]);
        float xh = mi * xi + (1.f - mi) * (gx * xlast + (1.f - gx) * xm);
        size_t row = (size_t)ll * 128 + b;           // l-major chunk row
        Xcat[row * 1024 + h]       = f2bf(xh);
        Xcat[row * 1024 + 512 + h] = f2bf(mi);
        Dbuf[row * 512 + h]        = f2bf(delta);
        xlast = mi * xi + (1.f - mi) * xlast;
        dprev = delta; mprev = mi;
    }
    xlastC[g] = xlast; dprevC[g] = dprev; mprevC[g] = mprev; tprevC[g] = tprev;
}

// ---------------- tiled MFMA GEMM, A (MxK) row-major bf16, BT (NxK) row-major bf16 ----
// MODE 0: bf16 out = acc+bias ; MODE 1: fp16 out = exp(-relu(acc+bias)) ;
// MODE 2: f32 out = acc+bias with chunk-row remap (l-major -> (b,l))
template <int MODE>
__global__ __launch_bounds__(256) void gemm_bt(const bf16* __restrict__ A,
                                               const bf16* __restrict__ BT,
                                               const float* __restrict__ bias,
                                               void* __restrict__ Cout,
                                               int N, int K, int q) {
    const int nb = N >> 7;
    int bn = blockIdx.x % nb, bm = blockIdx.x / nb;
    __shared__ bf16 As[4096];   // [kc][row] 16B chunks
    __shared__ bf16 Bs[4096];
    int tid = threadIdx.x, lane = tid & 63, w = tid >> 6;
    int wm = w >> 1, wn = w & 1;
    int quad = lane >> 4, l15 = lane & 15;
    f32x4 acc[4][4];
    #pragma unroll
    for (int i = 0; i < 4; ++i)
        #pragma unroll
        for (int j = 0; j < 4; ++j) acc[i][j] = (f32x4){0.f, 0.f, 0.f, 0.f};

    for (int k0 = 0; k0 < K; k0 += 32) {
        bf16x8 av[2], bv[2];
        #pragma unroll
        for (int cc = 0; cc < 2; ++cc) {
            int c = tid + cc * 256;
            int row = c >> 2, kc = c & 3;
            av[cc] = *(const bf16x8*)(A  + (size_t)(bm * 128 + row) * K + k0 + kc * 8);
            bv[cc] = *(const bf16x8*)(BT + (size_t)(bn * 128 + row) * K + k0 + kc * 8);
        }
        __syncthreads();
        #pragma unroll
        for (int cc = 0; cc < 2; ++cc) {
            int c = tid + cc * 256;
            int row = c >> 2, kc = c & 3;
            *(bf16x8*)&As[(kc * 128 + row) * 8] = av[cc];
            *(bf16x8*)&Bs[(kc * 128 + row) * 8] = bv[cc];
        }
        __syncthreads();
        bf16x8 af[4], bfr[4];
        #pragma unroll
        for (int mt = 0; mt < 4; ++mt)
            af[mt] = *(const bf16x8*)&As[(quad * 128 + wm * 64 + mt * 16 + l15) * 8];
        #pragma unroll
        for (int nt = 0; nt < 4; ++nt)
            bfr[nt] = *(const bf16x8*)&Bs[(quad * 128 + wn * 64 + nt * 16 + l15) * 8];
        #pragma unroll
        for (int mt = 0; mt < 4; ++mt)
            #pragma unroll
            for (int nt = 0; nt < 4; ++nt)
                acc[mt][nt] = MFMA16(af[mt], bfr[nt], acc[mt][nt]);
    }
    int row0 = bm * 128 + wm * 64, col0 = bn * 128 + wn * 64;
    #pragma unroll
    for (int mt = 0; mt < 4; ++mt) {
        #pragma unroll
        for (int nt = 0; nt < 4; ++nt) {
            int col = col0 + nt * 16 + l15;
            float bvf = sf(bias[col]);
            #pragma unroll
            for (int r = 0; r < 4; ++r) {
                int row = row0 + mt * 16 + quad * 4 + r;
                float v = acc[mt][nt][r] + bvf;
                if (MODE == 1)
                    ((__half*)Cout)[(size_t)row * N + col] = __float2half(__expf(-fmaxf(v, 0.f)));
                else if (MODE == 2) {
                    int bb = row & 127, lloc = row >> 7;
                    ((float*)Cout)[(size_t)((bb << 8) + q * CH + lloc) * N + col] = v;
                } else
                    ((bf16*)Cout)[(size_t)row * N + col] = f2bf(v);
            }
        }
    }
}

// ---------------- sequential h-scan over one 32-step chunk ----------------
// 8 clusters x 4 WGs x 512 threads (8 waves/WG; 32 waves/cluster; wave wi owns
// cols [wi*16,+16) of each gate; 192 weight VGPRs/lane — no spill at <=256 cap).
// Cross-WG barrier = flag VECTOR: WG w release-stores epoch to its own word
// (parallel arrivals, no RMW chain — r7's fetch_add serialized 8 L2 round trips),
// relaxed polls of the 4-word line, ONE acquire load after spin (buffer_inv only;
// release store carries the wbl2). hseq/hcarry stores nontemporal to slim the wb.
__global__ __launch_bounds__(512, 1) void scan_kernel(
        const bf16* __restrict__ pre,      // (4096,1536) l-major
        const __half* __restrict__ gammaf, // (4096,512) l-major
        const bf16* __restrict__ WhT,      // (1536,512)
        bf16* __restrict__ hseq,           // (4096,512) l-major
        float* __restrict__ hcarry,        // (128,512)
        bf16* __restrict__ rbuf,           // [8][16][512] bf16
        bf16* __restrict__ hnbuf,          // [8][16][512] bf16
        unsigned* __restrict__ ctr) {      // this chunk's slot (512 uints, zeroed)
    int bx = blockIdx.x;
    int c = bx & 7, w = bx >> 3;           // cluster, WG-in-cluster (0..3)
    int tid = threadIdx.x, lane = tid & 63, v = tid >> 6;   // v in [0,8)
    int wi = (w << 3) | v;                 // 0..31: owns cols [wi*16,+16) per gate
    int quad = lane >> 4, l15 = lane & 15;
    __shared__ bf16 hb[16 * 520];          // full h, bf16 (MFMA A source)
    __shared__ bf16 rh[16 * 520];          // r*h, bf16 (MFMA A source)

    // stationary Wh B-fragments: B[n=l15][k=quad*8+j] per kf block of K=32
    bf16x8 whz[16], whr[16], whh[16];
    int col0 = wi * 16;
    #pragma unroll
    for (int kf = 0; kf < 16; ++kf) {
        int n = col0 + l15;
        whz[kf] = *(const bf16x8*)(WhT + (size_t)n * 512 + kf * 32 + quad * 8);
        whr[kf] = *(const bf16x8*)(WhT + (size_t)(512 + n) * 512 + kf * 32 + quad * 8);
        whh[kf] = *(const bf16x8*)(WhT + (size_t)(1024 + n) * 512 + kf * 32 + quad * 8);
    }

    bf16* rclu = rbuf  + (size_t)c * 16 * 512;
    bf16* hclu = hnbuf + (size_t)c * 16 * 512;
    const unsigned short* gus = (const unsigned short*)gammaf;
    unsigned* fA = ctr + c * 64;           // 4 flag words (one per WG), 256B/cluster
    unsigned* fB = ctr + c * 64 + 32;

    // init: hb = bf16(hcarry * gamma(step 0)); owned f32 state in hfo
    for (int i = tid; i < 16 * 512; i += 512) {
        int row = i >> 9, col = i & 511;
        int brow = c * 16 + row;
        float g0 = __half2float(gammaf[(size_t)brow * 512 + col]);
        hb[row * 520 + col] = f2bf(hcarry[(size_t)brow * 512 + col] * g0);
    }
    float hfo[4];
    #pragma unroll
    for (int r = 0; r < 4; ++r) {
        int brow = c * 16 + quad * 4 + r;
        int cc = col0 + l15;
        float g0 = __half2float(gammaf[(size_t)brow * 512 + cc]);
        hfo[r] = hcarry[(size_t)brow * 512 + cc] * g0;
    }
    __syncthreads();

    int prow = tid >> 5;                   // phase B/C tile: row, 16 contiguous cols
    int pcol = (tid & 31) << 4;

    for (int t = 0; t < CH; ++t) {
        unsigned ep = (unsigned)(t + 1);
        bool lastt = (t == CH - 1);
        // ---- register prefetch (consumed after the fences; fence-immune) ----
        float pz[4], prr[4], ph[4], gow[4];
        #pragma unroll
        for (int r = 0; r < 4; ++r) {
            int brow = c * 16 + quad * 4 + r;
            size_t pb = ((size_t)t * 128 + brow) * 1536;
            int cc = col0 + l15;
            pz[r]  = bf2f(pre[pb + cc]);
            prr[r] = bf2f(pre[pb + 512 + cc]);
            ph[r]  = bf2f(pre[pb + 1024 + cc]);
            gow[r] = lastt ? 1.f
                   : __half2float(gammaf[((size_t)(t + 1) * 128 + brow) * 512 + cc]);
        }
        u16x8 gt[2];
        {
            size_t gb = ((size_t)(lastt ? t : t + 1) * 128 + c * 16 + prow) * 512 + pcol;
            #pragma unroll
            for (int j = 0; j < 2; ++j) gt[j] = *(const u16x8*)(gus + gb + j * 8);
        }
        // ---- phase A: z local, publish r (bf16) ----
        f32x4 az = (f32x4){0.f,0.f,0.f,0.f}, ar = az;
        #pragma unroll
        for (int kf = 0; kf < 16; ++kf) {
            bf16x8 a = *(const bf16x8*)&hb[l15 * 520 + kf * 32 + quad * 8];
            az = MFMA16(a, whz[kf], az);
            ar = MFMA16(a, whr[kf], ar);
        }
        float zv[4];
        #pragma unroll
        for (int r = 0; r < 4; ++r) {
            zv[r] = 1.f / (1.f + __expf(-(az[r] + pz[r])));
            float rv = 1.f / (1.f + __expf(-(ar[r] + prr[r])));
            rclu[(quad * 4 + r) * 512 + col0 + l15] = f2bf(rv);
        }
        __syncthreads();                   // all waves' stores complete (vmcnt0)
        if (tid == 0) {
            __hip_atomic_store(&fA[w], ep, __ATOMIC_RELEASE, __HIP_MEMORY_SCOPE_AGENT);
            int guard = 0;
            for (;;) {
                bool ok = true;
                #pragma unroll
                for (int j = 0; j < 4; ++j)
                    ok &= (__hip_atomic_load(&fA[j], __ATOMIC_RELAXED,
                                             __HIP_MEMORY_SCOPE_AGENT) >= ep);
                if (ok || ++guard >= (1 << 17)) break;
                __builtin_amdgcn_s_sleep(1);
            }
            (void)__hip_atomic_load(&fA[0], __ATOMIC_ACQUIRE, __HIP_MEMORY_SCOPE_AGENT);
        }
        __syncthreads();
        // ---- phase B: rh = bf16(r ⊙ h); ht; h_new local; publish h_new (bf16) ----
        #pragma unroll
        for (int j = 0; j < 2; ++j) {
            bf16x8 r8 = *(const bf16x8*)&rclu[prow * 512 + pcol + j * 8];
            bf16x8 h8 = *(const bf16x8*)&hb[prow * 520 + pcol + j * 8];
            bf16x8 o;
            #pragma unroll
            for (int e = 0; e < 8; ++e) o[e] = f2bs(bs2f(r8[e]) * bs2f(h8[e]));
            *(bf16x8*)&rh[prow * 520 + pcol + j * 8] = o;
        }
        __syncthreads();
        f32x4 ah = (f32x4){0.f,0.f,0.f,0.f};
        #pragma unroll
        for (int kf = 0; kf < 16; ++kf) {
            bf16x8 a = *(const bf16x8*)&rh[l15 * 520 + kf * 32 + quad * 8];
            ah = MFMA16(a, whh[kf], ah);
        }
        #pragma unroll
        for (int r = 0; r < 4; ++r) {
            int row = quad * 4 + r;
            int brow = c * 16 + row;
            int cc = col0 + l15;
            float x = ah[r] + ph[r];
            float e = __expf(-2.f * fabsf(x));
            float th = copysignf((1.f - e) / (1.f + e), x);
            float hn = (1.f - zv[r]) * hfo[r] + zv[r] * th;
            bf16 hnb = f2bf(hn);
            hclu[row * 512 + cc] = hnb;
            __builtin_nontemporal_store(*(short*)&hnb,
                (short*)&hseq[((size_t)t * 128 + brow) * 512 + cc]);
            if (lastt)
                __builtin_nontemporal_store(hn, &hcarry[(size_t)brow * 512 + cc]);
            hfo[r] = hn * gow[r];
        }
        __syncthreads();
        if (tid == 0) {
            __hip_atomic_store(&fB[w], ep, __ATOMIC_RELEASE, __HIP_MEMORY_SCOPE_AGENT);
            int guard = 0;
            for (;;) {
                bool ok = true;
                #pragma unroll
                for (int j = 0; j < 4; ++j)
                    ok &= (__hip_atomic_load(&fB[j], __ATOMIC_RELAXED,
                                             __HIP_MEMORY_SCOPE_AGENT) >= ep);
                if (ok || ++guard >= (1 << 17)) break;
                __builtin_amdgcn_s_sleep(1);
            }
            (void)__hip_atomic_load(&fB[0], __ATOMIC_ACQUIRE, __HIP_MEMORY_SCOPE_AGENT);
        }
        __syncthreads();
        // ---- phase C: hb = bf16(h_new * gamma(t+1)) for all 512 cols ----
        #pragma unroll
        for (int j = 0; j < 2; ++j) {
            bf16x8 h8 = *(const bf16x8*)&hclu[prow * 512 + pcol + j * 8];
            bf16x8 o;
            #pragma unroll
            for (int e = 0; e < 8; ++e) {
                float g = lastt ? 1.f : h2f(gt[j][e]);
                o[e] = f2bs(bs2f(h8[e]) * g);
            }
            *(bf16x8*)&hb[prow * 520 + pcol + j * 8] = o;
        }
        __syncthreads();
    }
}

// ---------------- launcher ----------------

extern "C" void kernel_launch(void* const* d_in, const int* in_sizes, int n_in,
                              void* d_out, int out_size, void* d_ws, size_t ws_size,
                              hipStream_t stream) {
    const float* C     = (const float*)d_in[0];
    const float* t_in  = (const float*)d_in[1];
    const int*   mask  = (const int*)d_in[2];
    const float* Wx    = (const float*)d_in[3];
    const float* Wh    = (const float*)d_in[4];
    const float* Wm    = (const float*)d_in[5];
    const float* bvec  = (const float*)d_in[6];
    const float* w_gx  = (const float*)d_in[7];
    const float* b_gx  = (const float*)d_in[8];
    const float* W_gh  = (const float*)d_in[9];
    const float* b_gh  = (const float*)d_in[10];
    const float* W_out = (const float*)d_in[11];
    const float* b_out = (const float*)d_in[12];

    char* w = (char*)d_ws;                              // total used: ~41 MB
    unsigned* ctr   = (unsigned*)(w + 0);               //   16384 (8 chunk slots)
    float* hcarry   = (float*)(w + 16384);              //  262144
    float* xmean    = (float*)(w + 278528);             //  262144
    float* xlastC   = (float*)(w + 540672);             //  262144
    float* dprevC   = (float*)(w + 802816);             //  262144
    float* mprevC   = (float*)(w + 1064960);            //  262144
    float* tprevC   = (float*)(w + 1327104);            //  262144
    bf16*  wcatT    = (bf16*)(w + 1589248);             // 3145728
    bf16*  wghT     = (bf16*)(w + 4734976);             //  524288
    bf16*  whT      = (bf16*)(w + 5259264);             // 1572864
    bf16*  woutT    = (bf16*)(w + 6832128);             //  262144
    bf16*  Xcat     = (bf16*)(w + 7094272);             //  8388608 (chunk)
    bf16*  Dbuf     = (bf16*)(w + 15482880);            //  4194304 (chunk)
    bf16*  pre      = (bf16*)(w + 19677184);            // 12582912 (chunk)
    __half* gamma   = (__half*)(w + 32260096);          //  4194304 (chunk)
    bf16*  hseq     = (bf16*)(w + 36454400);            //  4194304 (chunk)
    bf16*  rbuf     = (bf16*)(w + 40648704);            //   131072
    bf16*  hnbuf    = (bf16*)(w + 40779776);            //   131072 -> ends 40,910,848

    hipMemsetAsync(w, 0, 278528, stream);               // ctr + hcarry

    build_wcatT<<<6144, 256, 0, stream>>>(Wx, Wm, wcatT);
    transpose_f2b<<<1024, 256, 0, stream>>>(W_gh, wghT, 512, 512);
    transpose_f2b<<<3072, 256, 0, stream>>>(Wh, whT, 512, 1536);
    transpose_f2b<<<512, 256, 0, stream>>>(W_out, woutT, 512, 256);
    xmean_kernel<<<256, 256, 0, stream>>>(mask, C, xmean);

    for (int q = 0; q < NQ; ++q) {
        prep_kernel<<<256, 256, 0, stream>>>(mask, C, t_in, w_gx, b_gx, xmean,
                                             xlastC, dprevC, mprevC, tprevC,
                                             Xcat, Dbuf, q);
        gemm_bt<0><<<32 * 12, 256, 0, stream>>>(Xcat, wcatT, bvec, (void*)pre, 1536, 1024, q);
        gemm_bt<1><<<32 * 4, 256, 0, stream>>>(Dbuf, wghT, b_gh, (void*)gamma, 512, 512, q);
        scan_kernel<<<32, 512, 0, stream>>>(pre, gamma, whT, hseq, hcarry,
                                            rbuf, hnbuf, ctr + q * 512);
        gemm_bt<2><<<32 * 2, 256, 0, stream>>>(hseq, woutT, b_out, d_out, 256, 512, q);
    }
}

// Round 10
// 2864.287 us; speedup vs baseline: 4.3461x; 1.2002x over previous
//
#include <hip/hip_runtime.h>
#include <hip/hip_bf16.h>
#include <hip/hip_fp16.h>
#include <stdint.h>

typedef short bf16x8 __attribute__((ext_vector_type(8)));
typedef unsigned short u16x8 __attribute__((ext_vector_type(8)));
typedef float f32x4  __attribute__((ext_vector_type(4)));
typedef __hip_bfloat16 bf16;
typedef unsigned long long u64;

#define MFMA16(a,b,c) __builtin_amdgcn_mfma_f32_16x16x32_bf16((a),(b),(c),0,0,0)

__device__ __forceinline__ float bf2f(bf16 x){ return __bfloat162float(x); }
__device__ __forceinline__ bf16  f2bf(float x){ return __float2bfloat16(x); }
__device__ __forceinline__ short f2bs(float x){ bf16 t = __float2bfloat16(x); return *(short*)&t; }
__device__ __forceinline__ float bs2f(short s){ bf16 t; *(short*)&t = s; return __bfloat162float(t); }
__device__ __forceinline__ float h2f(unsigned short u){ __half t; *(unsigned short*)&t = u; return __half2float(t); }
// sanitize raw f32 inputs: kill NaN/inf
__device__ __forceinline__ float sf(float x){ return (fabsf(x) < 1e30f) ? x : 0.f; }

// Problem: B=128, L=256, H=512, OUT=256. All I/O float32. Chunked: 8 x 32 steps.
#define NB   128
#define NL   256
#define CH   32     // steps per chunk
#define MCH  4096   // rows per chunk = CH*NB
#define NQ   8      // chunks

// ---------------- weight preprocessing (f32 in -> bf16 internal) ----------------

__global__ void build_wcatT(const float* __restrict__ Wx, const float* __restrict__ Wm,
                            bf16* __restrict__ dst) {
    int i = blockIdx.x * 256 + threadIdx.x;
    if (i >= 1536 * 1024) return;
    int n = i >> 10, k = i & 1023;
    float v = (k < 512) ? Wx[k * 1536 + n] : Wm[(k - 512) * 1536 + n];
    dst[i] = f2bf(sf(v));
}

__global__ void transpose_f2b(const float* __restrict__ src, bf16* __restrict__ dst,
                              int R, int C) {
    int i = blockIdx.x * 256 + threadIdx.x;
    if (i >= R * C) return;
    int r = i % R, c = i / R;
    dst[i] = f2bf(sf(src[r * C + c]));
}

// ---------------- x-path (h-independent) ----------------

__global__ void xmean_kernel(const int* __restrict__ mask, const float* __restrict__ Cmat,
                             float* __restrict__ xmean) {
    int g = blockIdx.x * 256 + threadIdx.x;   // (b,h)
    int b = g >> 9, h = g & 511;
    float s = 0.f, cnt = 0.f;
    for (int l = 0; l < NL; ++l) {
        int m = mask[(size_t)((b << 8) + l) * 512 + h];
        if (m) { s += sf(Cmat[(l << 9) + h]); cnt += 1.f; }
    }
    xmean[g] = s / fmaxf(cnt, 1.f);
}

__global__ void prep_kernel(const int* __restrict__ mask, const float* __restrict__ Cmat,
                            const float* __restrict__ t_in,
                            const float* __restrict__ w_gx, const float* __restrict__ b_gx,
                            const float* __restrict__ xmean,
                            float* __restrict__ xlastC, float* __restrict__ dprevC,
                            float* __restrict__ mprevC, float* __restrict__ tprevC,
                            bf16* __restrict__ Xcat,   // (4096,1024) l-major: [x_hat|m]
                            bf16* __restrict__ Dbuf,   // (4096,512) l-major: delta
                            int q) {
    int g = blockIdx.x * 256 + threadIdx.x;
    int b = g >> 9, h = g & 511;
    float wg = sf(w_gx[h]), bg = sf(b_gx[h]);
    float xm = xmean[g];
    float xlast, dprev, mprev, tprev;
    if (q == 0) { xlast = xm; dprev = 0.f; mprev = 1.f; tprev = 0.f; }
    else { xlast = xlastC[g]; dprev = dprevC[g]; mprev = mprevC[g]; tprev = tprevC[g]; }
    for (int ll = 0; ll < CH; ++ll) {
        int l = q * CH + ll;
        float tc = sf(t_in[(b << 8) + l]);
        float dtv = (l == 0) ? 0.f : (tc - tprev);
        tprev = tc;
        float mi = (float)mask[(size_t)((b << 8) + l) * 512 + h];
        float delta = dtv + (1.f - mprev) * dprev;
        float gx = __expf(-fmaxf(wg * delta + bg, 0.f));
        float xi = sf(Cmat[(l << 9) + h]);
        float xh = mi * xi + (1.f - mi) * (gx * xlast + (1.f - gx) * xm);
        size_t row = (size_t)ll * 128 + b;           // l-major chunk row
        Xcat[row * 1024 + h]       = f2bf(xh);
        Xcat[row * 1024 + 512 + h] = f2bf(mi);
        Dbuf[row * 512 + h]        = f2bf(delta);
        xlast = mi * xi + (1.f - mi) * xlast;
        dprev = delta; mprev = mi;
    }
    xlastC[g] = xlast; dprevC[g] = dprev; mprevC[g] = mprev; tprevC[g] = tprev;
}

// ---------------- tiled MFMA GEMM, A (MxK) row-major bf16, BT (NxK) row-major bf16 ----
// MODE 0: bf16 out = acc+bias ; MODE 1: fp16 out = exp(-relu(acc+bias)) ;
// MODE 2: f32 out = acc+bias with chunk-row remap (l-major -> (b,l))
template <int MODE>
__global__ __launch_bounds__(256) void gemm_bt(const bf16* __restrict__ A,
                                               const bf16* __restrict__ BT,
                                               const float* __restrict__ bias,
                                               void* __restrict__ Cout,
                                               int N, int K, int q) {
    const int nb = N >> 7;
    int bn = blockIdx.x % nb, bm = blockIdx.x / nb;
    __shared__ bf16 As[4096];   // [kc][row] 16B chunks
    __shared__ bf16 Bs[4096];
    int tid = threadIdx.x, lane = tid & 63, w = tid >> 6;
    int wm = w >> 1, wn = w & 1;
    int quad = lane >> 4, l15 = lane & 15;
    f32x4 acc[4][4];
    #pragma unroll
    for (int i = 0; i < 4; ++i)
        #pragma unroll
        for (int j = 0; j < 4; ++j) acc[i][j] = (f32x4){0.f, 0.f, 0.f, 0.f};

    for (int k0 = 0; k0 < K; k0 += 32) {
        bf16x8 av[2], bv[2];
        #pragma unroll
        for (int cc = 0; cc < 2; ++cc) {
            int c = tid + cc * 256;
            int row = c >> 2, kc = c & 3;
            av[cc] = *(const bf16x8*)(A  + (size_t)(bm * 128 + row) * K + k0 + kc * 8);
            bv[cc] = *(const bf16x8*)(BT + (size_t)(bn * 128 + row) * K + k0 + kc * 8);
        }
        __syncthreads();
        #pragma unroll
        for (int cc = 0; cc < 2; ++cc) {
            int c = tid + cc * 256;
            int row = c >> 2, kc = c & 3;
            *(bf16x8*)&As[(kc * 128 + row) * 8] = av[cc];
            *(bf16x8*)&Bs[(kc * 128 + row) * 8] = bv[cc];
        }
        __syncthreads();
        bf16x8 af[4], bfr[4];
        #pragma unroll
        for (int mt = 0; mt < 4; ++mt)
            af[mt] = *(const bf16x8*)&As[(quad * 128 + wm * 64 + mt * 16 + l15) * 8];
        #pragma unroll
        for (int nt = 0; nt < 4; ++nt)
            bfr[nt] = *(const bf16x8*)&Bs[(quad * 128 + wn * 64 + nt * 16 + l15) * 8];
        #pragma unroll
        for (int mt = 0; mt < 4; ++mt)
            #pragma unroll
            for (int nt = 0; nt < 4; ++nt)
                acc[mt][nt] = MFMA16(af[mt], bfr[nt], acc[mt][nt]);
    }
    int row0 = bm * 128 + wm * 64, col0 = bn * 128 + wn * 64;
    #pragma unroll
    for (int mt = 0; mt < 4; ++mt) {
        #pragma unroll
        for (int nt = 0; nt < 4; ++nt) {
            int col = col0 + nt * 16 + l15;
            float bvf = sf(bias[col]);
            #pragma unroll
            for (int r = 0; r < 4; ++r) {
                int row = row0 + mt * 16 + quad * 4 + r;
                float v = acc[mt][nt][r] + bvf;
                if (MODE == 1)
                    ((__half*)Cout)[(size_t)row * N + col] = __float2half(__expf(-fmaxf(v, 0.f)));
                else if (MODE == 2) {
                    int bb = row & 127, lloc = row >> 7;
                    ((float*)Cout)[(size_t)((bb << 8) + q * CH + lloc) * N + col] = v;
                } else
                    ((bf16*)Cout)[(size_t)row * N + col] = f2bf(v);
            }
        }
    }
}

// ---------------- sequential h-scan over one 32-step chunk ----------------
// 8 clusters x 4 WGs x 512 threads; wave wi owns cols [wi*16,+16) of each gate
// (192 weight VGPRs/lane, no spill). FENCE-FREE cross-WG exchange: all shared
// data (r-tile, hn-tile, flags) moves via RELAXED agent-scope atomics = LLC
// point accesses with NO buffer_inv / buffer_wbl2. Ordering: __syncthreads
// drains vmcnt(0) (data at LLC) before tid0 posts its flag; readers' loads
// issue after the poll load returns; LLC is the single serialization point.
// r9 BUG FIX: exchange tile rows are 128 u64 words (512 bf16), not 64 —
// r9's stride-64 indexing aliased adjacent batch rows (garbage h, absmax~1.23).
__global__ __launch_bounds__(512, 1) void scan_kernel(
        const bf16* __restrict__ pre,      // (4096,1536) l-major
        const __half* __restrict__ gammaf, // (4096,512) l-major
        const bf16* __restrict__ WhT,      // (1536,512)
        bf16* __restrict__ hseq,           // (4096,512) l-major
        float* __restrict__ hcarry,        // (128,512)
        u64* __restrict__ rbuf,            // [8][2048] u64 (= 16x512 bf16 tile)
        u64* __restrict__ hnbuf,           // [8][2048]
        unsigned* __restrict__ ctr) {      // this chunk's slot (512 uints, zeroed)
    int bx = blockIdx.x;
    int c = bx & 7, w = bx >> 3;           // cluster, WG-in-cluster (0..3)
    int tid = threadIdx.x, lane = tid & 63, v = tid >> 6;   // v in [0,8)
    int wi = (w << 3) | v;                 // 0..31: owns cols [wi*16,+16) per gate
    int quad = lane >> 4, l15 = lane & 15;
    __shared__ bf16 hb[16 * 520];          // full h bf16 (MFMA A source) / hn staging
    __shared__ bf16 rh[16 * 520];          // r*h bf16 (MFMA A source)

    // stationary Wh B-fragments: B[n=l15][k=quad*8+j] per kf block of K=32
    bf16x8 whz[16], whr[16], whh[16];
    int col0 = wi * 16;
    #pragma unroll
    for (int kf = 0; kf < 16; ++kf) {
        int n = col0 + l15;
        whz[kf] = *(const bf16x8*)(WhT + (size_t)n * 512 + kf * 32 + quad * 8);
        whr[kf] = *(const bf16x8*)(WhT + (size_t)(512 + n) * 512 + kf * 32 + quad * 8);
        whh[kf] = *(const bf16x8*)(WhT + (size_t)(1024 + n) * 512 + kf * 32 + quad * 8);
    }

    u64* rclu = rbuf  + (size_t)c * 2048;  // 16 rows x 128 words
    u64* hclu = hnbuf + (size_t)c * 2048;
    const unsigned short* gus = (const unsigned short*)gammaf;
    unsigned* fA = ctr + c * 64;           // 4 flag words per phase per cluster
    unsigned* fB = ctr + c * 64 + 32;

    // init: hb = bf16(hcarry * gamma(step 0)); owned f32 state in hfo
    for (int i = tid; i < 16 * 512; i += 512) {
        int row = i >> 9, col = i & 511;
        int brow = c * 16 + row;
        float g0 = __half2float(gammaf[(size_t)brow * 512 + col]);
        hb[row * 520 + col] = f2bf(hcarry[(size_t)brow * 512 + col] * g0);
    }
    float hfo[4];
    #pragma unroll
    for (int r = 0; r < 4; ++r) {
        int brow = c * 16 + quad * 4 + r;
        int cc = col0 + l15;
        float g0 = __half2float(gammaf[(size_t)brow * 512 + cc]);
        hfo[r] = hcarry[(size_t)brow * 512 + cc] * g0;
    }
    __syncthreads();

    // repack mapping (own-region words): 16 rows x 32 words of own 128-col region
    int rrow = tid >> 5, rword = tid & 31;
    // strip mapping (exchange-in / phase C): row prow, 16 cols from one region
    int prow = tid >> 5, pc16 = tid & 31, pcol = pc16 << 4, pregion = pc16 >> 3;

    for (int t = 0; t < CH; ++t) {
        unsigned ep = (unsigned)(t + 1);
        bool lastt = (t == CH - 1);
        // ---- register prefetch (plain cached loads; read-only, stays warm) ----
        float pz[4], prr[4], ph[4], gow[4];
        #pragma unroll
        for (int r = 0; r < 4; ++r) {
            int brow = c * 16 + quad * 4 + r;
            size_t pb = ((size_t)t * 128 + brow) * 1536;
            int cc = col0 + l15;
            pz[r]  = bf2f(pre[pb + cc]);
            prr[r] = bf2f(pre[pb + 512 + cc]);
            ph[r]  = bf2f(pre[pb + 1024 + cc]);
            gow[r] = lastt ? 1.f
                   : __half2float(gammaf[((size_t)(t + 1) * 128 + brow) * 512 + cc]);
        }
        u16x8 gt[2];
        {
            size_t gb = ((size_t)(lastt ? t : t + 1) * 128 + c * 16 + prow) * 512 + pcol;
            #pragma unroll
            for (int j = 0; j < 2; ++j) gt[j] = *(const u16x8*)(gus + gb + j * 8);
        }
        // ---- phase A: z local; rh(own cols) = bf16(sigmoid(r) * h) into LDS ----
        f32x4 az = (f32x4){0.f,0.f,0.f,0.f}, ar = az;
        #pragma unroll
        for (int kf = 0; kf < 16; ++kf) {
            bf16x8 a = *(const bf16x8*)&hb[l15 * 520 + kf * 32 + quad * 8];
            az = MFMA16(a, whz[kf], az);
            ar = MFMA16(a, whr[kf], ar);
        }
        float zv[4];
        #pragma unroll
        for (int r = 0; r < 4; ++r) {
            zv[r] = 1.f / (1.f + __expf(-(az[r] + pz[r])));
            float rv = 1.f / (1.f + __expf(-(ar[r] + prr[r])));
            rh[(quad * 4 + r) * 520 + col0 + l15] = f2bf(rv * hfo[r]);
        }
        __syncthreads();
        // publish own rh region: 1 u64/thread, relaxed agent atomic (LLC point store)
        {
            u64 wv = *(const u64*)&rh[rrow * 520 + w * 128 + rword * 4];
            __hip_atomic_store(&rclu[rrow * 128 + w * 32 + rword], wv,
                               __ATOMIC_RELAXED, __HIP_MEMORY_SCOPE_AGENT);
        }
        __syncthreads();                   // vmcnt(0): stores landed at LLC
        if (tid == 0) {
            __hip_atomic_store(&fA[w], ep, __ATOMIC_RELAXED, __HIP_MEMORY_SCOPE_AGENT);
            int guard = 0;
            for (;;) {
                bool ok = true;
                #pragma unroll
                for (int j = 0; j < 4; ++j)
                    ok &= (__hip_atomic_load(&fA[j], __ATOMIC_RELAXED,
                                             __HIP_MEMORY_SCOPE_AGENT) >= ep);
                if (ok || ++guard >= (1 << 16)) break;
                __builtin_amdgcn_s_sleep(1);
            }
        }
        __syncthreads();
        // gather peer rh strips (4 u64/thread from LLC)
        if (pregion != w) {
            #pragma unroll
            for (int j = 0; j < 4; ++j) {
                u64 wv = __hip_atomic_load(&rclu[prow * 128 + pc16 * 4 + j],
                                           __ATOMIC_RELAXED, __HIP_MEMORY_SCOPE_AGENT);
                *(u64*)&rh[prow * 520 + pcol + j * 4] = wv;
            }
        }
        __syncthreads();
        // ---- phase B: ht = tanh(pre3 + rh @ Wh3); hn; stage into hb ----
        f32x4 ah = (f32x4){0.f,0.f,0.f,0.f};
        #pragma unroll
        for (int kf = 0; kf < 16; ++kf) {
            bf16x8 a = *(const bf16x8*)&rh[l15 * 520 + kf * 32 + quad * 8];
            ah = MFMA16(a, whh[kf], ah);
        }
        #pragma unroll
        for (int r = 0; r < 4; ++r) {
            int row = quad * 4 + r;
            int cc = col0 + l15;
            float x = ah[r] + ph[r];
            float e = __expf(-2.f * fabsf(x));
            float th = copysignf((1.f - e) / (1.f + e), x);
            float hn = (1.f - zv[r]) * hfo[r] + zv[r] * th;
            hb[row * 520 + cc] = f2bf(hn);
            if (lastt) {
                int brow = c * 16 + row;
                __builtin_nontemporal_store(hn, &hcarry[(size_t)brow * 512 + cc]);
            }
            hfo[r] = hn * gow[r];
        }
        __syncthreads();
        // publish own hn region
        {
            u64 wv = *(const u64*)&hb[rrow * 520 + w * 128 + rword * 4];
            __hip_atomic_store(&hclu[rrow * 128 + w * 32 + rword], wv,
                               __ATOMIC_RELAXED, __HIP_MEMORY_SCOPE_AGENT);
        }
        __syncthreads();                   // vmcnt(0) drain before flag
        if (tid == 0) {
            __hip_atomic_store(&fB[w], ep, __ATOMIC_RELAXED, __HIP_MEMORY_SCOPE_AGENT);
            int guard = 0;
            for (;;) {
                bool ok = true;
                #pragma unroll
                for (int j = 0; j < 4; ++j)
                    ok &= (__hip_atomic_load(&fB[j], __ATOMIC_RELAXED,
                                             __HIP_MEMORY_SCOPE_AGENT) >= ep);
                if (ok || ++guard >= (1 << 16)) break;
                __builtin_amdgcn_s_sleep(1);
            }
        }
        __syncthreads();
        // ---- phase C: gather hn strips, write hseq (w0), apply gamma -> hb ----
        u64 hw[4];
        if (pregion != w) {
            #pragma unroll
            for (int j = 0; j < 4; ++j)
                hw[j] = __hip_atomic_load(&hclu[prow * 128 + pc16 * 4 + j],
                                          __ATOMIC_RELAXED, __HIP_MEMORY_SCOPE_AGENT);
        } else {
            #pragma unroll
            for (int j = 0; j < 4; ++j)
                hw[j] = *(const u64*)&hb[prow * 520 + pcol + j * 4];
        }
        if (w == 0) {
            int brow = c * 16 + prow;
            u64* hs = (u64*)&hseq[((size_t)t * 128 + brow) * 512 + pcol];
            #pragma unroll
            for (int j = 0; j < 4; ++j) __builtin_nontemporal_store(hw[j], &hs[j]);
        }
        #pragma unroll
        for (int j = 0; j < 4; ++j) {
            u16x8* gp = (u16x8*)&gt[0];    // 16 gammas for this strip
            short o4[4];
            #pragma unroll
            for (int e = 0; e < 4; ++e) {
                short hv = (short)((hw[j] >> (16 * e)) & 0xFFFF);
                float g = lastt ? 1.f : h2f(((unsigned short*)gp)[j * 4 + e]);
                o4[e] = f2bs(bs2f(hv) * g);
            }
            u64 ov = ((u64)(unsigned short)o4[0]) | ((u64)(unsigned short)o4[1] << 16)
                   | ((u64)(unsigned short)o4[2] << 32) | ((u64)(unsigned short)o4[3] << 48);
            *(u64*)&hb[prow * 520 + pcol + j * 4] = ov;
        }
        __syncthreads();
    }
}

// ---------------- launcher ----------------

extern "C" void kernel_launch(void* const* d_in, const int* in_sizes, int n_in,
                              void* d_out, int out_size, void* d_ws, size_t ws_size,
                              hipStream_t stream) {
    const float* C     = (const float*)d_in[0];
    const float* t_in  = (const float*)d_in[1];
    const int*   mask  = (const int*)d_in[2];
    const float* Wx    = (const float*)d_in[3];
    const float* Wh    = (const float*)d_in[4];
    const float* Wm    = (const float*)d_in[5];
    const float* bvec  = (const float*)d_in[6];
    const float* w_gx  = (const float*)d_in[7];
    const float* b_gx  = (const float*)d_in[8];
    const float* W_gh  = (const float*)d_in[9];
    const float* b_gh  = (const float*)d_in[10];
    const float* W_out = (const float*)d_in[11];
    const float* b_out = (const float*)d_in[12];

    char* w = (char*)d_ws;                              // total used: ~41 MB
    unsigned* ctr   = (unsigned*)(w + 0);               //   16384 (8 chunk slots)
    float* hcarry   = (float*)(w + 16384);              //  262144
    float* xmean    = (float*)(w + 278528);             //  262144
    float* xlastC   = (float*)(w + 540672);             //  262144
    float* dprevC   = (float*)(w + 802816);             //  262144
    float* mprevC   = (float*)(w + 1064960);            //  262144
    float* tprevC   = (float*)(w + 1327104);            //  262144
    bf16*  wcatT    = (bf16*)(w + 1589248);             // 3145728
    bf16*  wghT     = (bf16*)(w + 4734976);             //  524288
    bf16*  whT      = (bf16*)(w + 5259264);             // 1572864
    bf16*  woutT    = (bf16*)(w + 6832128);             //  262144
    bf16*  Xcat     = (bf16*)(w + 7094272);             //  8388608 (chunk)
    bf16*  Dbuf     = (bf16*)(w + 15482880);            //  4194304 (chunk)
    bf16*  pre      = (bf16*)(w + 19677184);            // 12582912 (chunk)
    __half* gamma   = (__half*)(w + 32260096);          //  4194304 (chunk)
    bf16*  hseq     = (bf16*)(w + 36454400);            //  4194304 (chunk)
    u64*   rbuf     = (u64*)(w + 40648704);             //   131072
    u64*   hnbuf    = (u64*)(w + 40779776);             //   131072 -> ends 40,910,848

    hipMemsetAsync(w, 0, 278528, stream);               // ctr + hcarry

    build_wcatT<<<6144, 256, 0, stream>>>(Wx, Wm, wcatT);
    transpose_f2b<<<1024, 256, 0, stream>>>(W_gh, wghT, 512, 512);
    transpose_f2b<<<3072, 256, 0, stream>>>(Wh, whT, 512, 1536);
    transpose_f2b<<<512, 256, 0, stream>>>(W_out, woutT, 512, 256);
    xmean_kernel<<<256, 256, 0, stream>>>(mask, C, xmean);

    for (int q = 0; q < NQ; ++q) {
        prep_kernel<<<256, 256, 0, stream>>>(mask, C, t_in, w_gx, b_gx, xmean,
                                             xlastC, dprevC, mprevC, tprevC,
                                             Xcat, Dbuf, q);
        gemm_bt<0><<<32 * 12, 256, 0, stream>>>(Xcat, wcatT, bvec, (void*)pre, 1536, 1024, q);
        gemm_bt<1><<<32 * 4, 256, 0, stream>>>(Dbuf, wghT, b_gh, (void*)gamma, 512, 512, q);
        scan_kernel<<<32, 512, 0, stream>>>(pre, gamma, whT, hseq, hcarry,
                                            rbuf, hnbuf, ctr + q * 512);
        gemm_bt<2><<<32 * 2, 256, 0, stream>>>(hseq, woutT, b_out, d_out, 256, 512, q);
    }
}